// Round 1
// baseline (139.578 us; speedup 1.0000x reference)
//
#include <hip/hip_runtime.h>

// out[i] = x[i] * scale, vectorized float4. N is divisible by 4 for this
// problem (224*224 = 50176 ≡ 0 mod 4), but a scalar tail path is kept for
// robustness.
__global__ void __launch_bounds__(256) scale_f32x4_kernel(
    const float4* __restrict__ x4, float4* __restrict__ o4, int n4, float scale) {
    int i = blockIdx.x * blockDim.x + threadIdx.x;
    if (i < n4) {
        float4 v = x4[i];
        v.x *= scale;
        v.y *= scale;
        v.z *= scale;
        v.w *= scale;
        o4[i] = v;
    }
}

__global__ void scale_f32_tail_kernel(
    const float* __restrict__ x, float* __restrict__ o, int start, int n, float scale) {
    int i = start + blockIdx.x * blockDim.x + threadIdx.x;
    if (i < n) {
        o[i] = x[i] * scale;
    }
}

extern "C" void kernel_launch(void* const* d_in, const int* in_sizes, int n_in,
                              void* d_out, int out_size, void* d_ws, size_t ws_size,
                              hipStream_t stream) {
    const float* x = (const float*)d_in[0];
    float* out = (float*)d_out;
    const int n = in_sizes[0];

    // Reference: x / (H*W + 1e-9), H=W=224. Compute reciprocal in double,
    // round once to f32.
    const double denom = 224.0 * 224.0 + 1e-9;
    const float scale = (float)(1.0 / denom);

    const int n4 = n / 4;
    if (n4 > 0) {
        const int block = 256;
        const int grid = (n4 + block - 1) / block;
        scale_f32x4_kernel<<<grid, block, 0, stream>>>(
            (const float4*)x, (float4*)out, n4, scale);
    }
    const int tail_start = n4 * 4;
    const int tail = n - tail_start;
    if (tail > 0) {
        scale_f32_tail_kernel<<<1, 64, 0, stream>>>(x, out, tail_start, n, scale);
    }
}